// Round 4
// baseline (92.416 us; speedup 1.0000x reference)
//
#include <hip/hip_runtime.h>

// LIF recurrence: mem = 0.9*mem + x; spike = (mem >= 1); record spike & mem;
// mem -= spike. T=20 steps, elementwise-independent -> one thread per float4.
//
// Output layout (concatenated flat, return order):
//   out[0          .. T*N-1]   = spike_trains  [T][64][8192]
//   out[T*N        .. 2*T*N-1] = membrane_pot  [T][64][8192]
//
// R6: DISCRIMINATING PROBE (intentionally redundant, correctness-preserving).
//   Four structurally different kernels (NT/plain stores, 1x/4x occupancy,
//   interleaved/phase-split streams) all land at 88-92 us, within the
//   52-55 us run-to-run spread of the harness's per-iteration poison fill.
//   Two live hypotheses:
//     H1: kernel sustains only ~2.5 TB/s (35 us) for an unidentified
//         pattern- and occupancy-invariant reason.
//     H2: kernel is already near the 14 us HBM floor; the remaining
//         dur_us is fixed harness work; all prior deltas were fill noise.
//   This kernel stores BOTH output streams TWICE (second pass re-stores
//   bit-identical values from the register buffer; spikes re-derived as
//   membuf[t] >= 1.0 which equals the phase-1 spike exactly). A compiler
//   memory barrier between passes prevents dead-store elimination.
//   Final memory contents identical -> absmax must stay 0.0.
//   Prediction: H1 -> dur_us ~120-128 AND kernel appears in top-5 counters;
//               H2 -> dur_us ~100-104, kernel still absent.
//
// Numerics: forced mul-then-add rounding (__fmul_rn/__fadd_rn), no FMA
// contraction -- matches numpy fp32 exactly (absmax=0.0 in R4/R5).

#define TSTEPS 20

typedef float v4f __attribute__((ext_vector_type(4)));

__global__ __launch_bounds__(256) void
TemporalEncoding_57672820850797_kernel(const v4f* __restrict__ x,
                                       float* __restrict__ out, int n4) {
    int i = blockIdx.x * blockDim.x + threadIdx.x;  // float4 index
    if (i >= n4) return;

    const v4f xv = x[i];
    v4f* const spikes_base = reinterpret_cast<v4f*>(out) + i;
    v4f* const mems_base   = spikes_base + (size_t)TSTEPS * n4;

    float m0 = 0.f, m1 = 0.f, m2 = 0.f, m3 = 0.f;
    v4f membuf[TSTEPS];  // fully unrolled static indexing -> registers

    // ---- Pass A, phase 1: recurrence + spike stores ----
    v4f* sp = spikes_base;
#pragma unroll
    for (int t = 0; t < TSTEPS; ++t) {
        m0 = __fadd_rn(__fmul_rn(0.9f, m0), xv.x);
        m1 = __fadd_rn(__fmul_rn(0.9f, m1), xv.y);
        m2 = __fadd_rn(__fmul_rn(0.9f, m2), xv.z);
        m3 = __fadd_rn(__fmul_rn(0.9f, m3), xv.w);

        float s0 = (m0 >= 1.0f) ? 1.0f : 0.0f;
        float s1 = (m1 >= 1.0f) ? 1.0f : 0.0f;
        float s2 = (m2 >= 1.0f) ? 1.0f : 0.0f;
        float s3 = (m3 >= 1.0f) ? 1.0f : 0.0f;

        v4f sv; sv.x = s0; sv.y = s1; sv.z = s2; sv.w = s3;
        *sp = sv;
        sp += n4;

        v4f mv; mv.x = m0; mv.y = m1; mv.z = m2; mv.w = m3;
        membuf[t] = mv;

        m0 -= s0;
        m1 -= s1;
        m2 -= s2;
        m3 -= s3;
    }

    // ---- Pass A, phase 2: membrane stores ----
#pragma unroll
    for (int t = 0; t < TSTEPS; ++t) {
        mems_base[(size_t)t * n4] = membuf[t];
    }

    // Compiler memory barrier: a potential reader of all prior stores, so
    // DSE cannot delete pass A even though pass B overwrites the same
    // addresses (with identical values).
    asm volatile("" ::: "memory");

    // ---- Pass B (probe): re-store both streams, bit-identical values ----
    sp = spikes_base;
#pragma unroll
    for (int t = 0; t < TSTEPS; ++t) {
        const v4f mv = membuf[t];
        v4f sv;
        sv.x = (mv.x >= 1.0f) ? 1.0f : 0.0f;  // == phase-1 spike exactly
        sv.y = (mv.y >= 1.0f) ? 1.0f : 0.0f;
        sv.z = (mv.z >= 1.0f) ? 1.0f : 0.0f;
        sv.w = (mv.w >= 1.0f) ? 1.0f : 0.0f;
        *sp = sv;
        mems_base[(size_t)t * n4] = mv;
        sp += n4;
    }
}

extern "C" void kernel_launch(void* const* d_in, const int* in_sizes, int n_in,
                              void* d_out, int out_size, void* d_ws, size_t ws_size,
                              hipStream_t stream) {
    const float* x = (const float*)d_in[0];
    float* out = (float*)d_out;
    const int n = in_sizes[0];       // 64*8192 = 524288
    const int n4 = n / 4;            // 131072 float4 lanes
    const int block = 256;
    const int grid = (n4 + block - 1) / block;  // 512 blocks
    TemporalEncoding_57672820850797_kernel<<<grid, block, 0, stream>>>(
        (const v4f*)x, out, n4);
}

// Round 5
// 88.060 us; speedup vs baseline: 1.0495x; 1.0495x over previous
//
#include <hip/hip_runtime.h>

// LIF recurrence: mem = 0.9*mem + x; spike = (mem >= 1); record spike & mem;
// mem -= spike. T=20 steps, elementwise-independent -> one thread per float4.
//
// Output layout (concatenated flat, return order):
//   out[0          .. T*N-1]   = spike_trains  [T][64][8192]
//   out[T*N        .. 2*T*N-1] = membrane_pot  [T][64][8192]
//
// R7: restore R4 (best verified variant) after the R6 discriminating probe.
//   Session findings (R2-R6):
//   - NT vs plain stores: plain slightly better (~-2.4 us). NT reverted.
//   - 4x occupancy via time-split recompute: zero delta AND broke bit-
//     exactness (replay diverged through the reset nonlinearity). Reverted.
//   - Phase-splitting the two output streams: zero delta. Reverted.
//   - R6 probe: doubling store traffic cost only +4 us and the kernel never
//     appears in the top-5 counter rows (<52 us) -> the kernel dispatch is
//     already near its ~14 us HBM write floor (86 MB moved); the ~88 us
//     dur_us is dominated by the harness's per-iteration 335 MB poison
//     fill (~53 us @ 6.2 TB/s) plus fixed overhead. All R2-R5 deltas were
//     within the fill's +-2 us run-to-run noise.
//   Conclusion: kernel-side roofline reached; keep the simplest variant.
//
// Numerics: forced mul-then-add rounding (__fmul_rn/__fadd_rn) to match
// numpy fp32 exactly -- FMA contraction can flip the >=1.0 threshold by
// 1 ulp. This exact sequence measured absmax=0.0 in R4/R5/R6.

#define TSTEPS 20

typedef float v4f __attribute__((ext_vector_type(4)));

__global__ __launch_bounds__(256) void
TemporalEncoding_57672820850797_kernel(const v4f* __restrict__ x,
                                       float* __restrict__ out, int n4) {
    int i = blockIdx.x * blockDim.x + threadIdx.x;  // float4 index
    if (i >= n4) return;

    const v4f xv = x[i];
    v4f* __restrict__ spikes = reinterpret_cast<v4f*>(out) + i;
    v4f* __restrict__ mems   = reinterpret_cast<v4f*>(out) + (size_t)TSTEPS * n4 + i;

    float m0 = 0.f, m1 = 0.f, m2 = 0.f, m3 = 0.f;

#pragma unroll
    for (int t = 0; t < TSTEPS; ++t) {
        // mem = 0.9*mem + x, with separate rounding steps (no FMA contraction)
        m0 = __fadd_rn(__fmul_rn(0.9f, m0), xv.x);
        m1 = __fadd_rn(__fmul_rn(0.9f, m1), xv.y);
        m2 = __fadd_rn(__fmul_rn(0.9f, m2), xv.z);
        m3 = __fadd_rn(__fmul_rn(0.9f, m3), xv.w);

        float s0 = (m0 >= 1.0f) ? 1.0f : 0.0f;
        float s1 = (m1 >= 1.0f) ? 1.0f : 0.0f;
        float s2 = (m2 >= 1.0f) ? 1.0f : 0.0f;
        float s3 = (m3 >= 1.0f) ? 1.0f : 0.0f;

        v4f sv; sv.x = s0; sv.y = s1; sv.z = s2; sv.w = s3;
        v4f mv; mv.x = m0; mv.y = m1; mv.z = m2; mv.w = m3;
        *spikes = sv;   // plain store: completes into L2/L3, drains at WB BW
        *mems   = mv;
        spikes += n4;
        mems   += n4;

        // reset: mem -= spike*thr  (thr = 1.0, exact subtraction)
        m0 -= s0;
        m1 -= s1;
        m2 -= s2;
        m3 -= s3;
    }
}

extern "C" void kernel_launch(void* const* d_in, const int* in_sizes, int n_in,
                              void* d_out, int out_size, void* d_ws, size_t ws_size,
                              hipStream_t stream) {
    const float* x = (const float*)d_in[0];
    float* out = (float*)d_out;
    const int n = in_sizes[0];       // 64*8192 = 524288
    const int n4 = n / 4;            // 131072 float4 lanes
    const int block = 256;
    const int grid = (n4 + block - 1) / block;  // 512 blocks
    TemporalEncoding_57672820850797_kernel<<<grid, block, 0, stream>>>(
        (const v4f*)x, out, n4);
}